// Round 10
// baseline (282.483 us; speedup 1.0000x reference)
//
#include <hip/hip_runtime.h>

#define NG 20000

// single-instruction rotate (v_alignbit_b32): rotl(x,r) == alignbit(x,x,32-r)
__device__ __forceinline__ unsigned rotl32(unsigned x, int r) {
  return __builtin_amdgcn_alignbit(x, x, 32 - r);
}

// ---------- JAX threefry2x32, key = (0, 42) ----------
__device__ __forceinline__ void threefry2x32(unsigned x0, unsigned x1,
                                             unsigned& o0, unsigned& o1) {
  const unsigned ks0 = 0u;
  const unsigned ks1 = 42u;
  const unsigned ks2 = 0x1BD11BDAu ^ 0u ^ 42u;
  x0 += ks0; x1 += ks1;
#define TFR(r) { x0 += x1; x1 = rotl32(x1, (r)); x1 ^= x0; }
  TFR(13) TFR(15) TFR(26) TFR(6)
  x0 += ks1; x1 += ks2 + 1u;
  TFR(17) TFR(29) TFR(16) TFR(24)
  x0 += ks2; x1 += ks0 + 2u;
  TFR(13) TFR(15) TFR(26) TFR(6)
  x0 += ks0; x1 += ks1 + 3u;
  TFR(17) TFR(29) TFR(16) TFR(24)
  x0 += ks1; x1 += ks2 + 4u;
  TFR(13) TFR(15) TFR(26) TFR(6)
  x0 += ks2; x1 += ks0 + 5u;
#undef TFR
  o0 = x0; o1 = x1;
}

// JAX threefry_partitionable: bits(i) = o0 ^ o1 of threefry((0,42),(0,i))
__device__ __forceinline__ unsigned tfbits(unsigned ctr) {
  unsigned o0, o1;
  threefry2x32(0u, ctr, o0, o1);
  return o0 ^ o1;
}

// fp32 fast-screen gumbel, constant-folded: g = -ln2*log2(-log2(u)) - ln(ln2)
__device__ __forceinline__ float gumbel32(unsigned bits) {
  float f = __uint_as_float((bits >> 9) | 0x3f800000u) - 1.0f;
  float u = fmaxf(f, 1.17549435e-38f);
  const float l2u = __log2f(u);                     // strictly < 0
  return fmaf(-0.69314718056f, __log2f(-l2u), 0.3665129206f);
}

// exact fp64 gumbel; u is a 23-bit dyadic rational, exact in double
__device__ __forceinline__ double gumbel64(unsigned bits) {
  float f = __uint_as_float((bits >> 9) | 0x3f800000u) - 1.0f;
  double u = (double)fmaxf(f, 1.17549435e-38f);
  return -log(-log(u));
}

// pack fp64 score (top 49 monotone bits) + 15-bit (32767-n): u64 max == (score, then smaller n)
__device__ __forceinline__ unsigned long long packcell(double v, int n) {
  unsigned long long u = (unsigned long long)__double_as_longlong(v);
  u = (u >> 63) ? ~u : (u | 0x8000000000000000ull);
  return (u & 0xFFFFFFFFFFFF8000ull) | (unsigned long long)(32767 - n);
}

// monotone fp32 pack (high 32) + gene index (low 32) for top-2 reduction
__device__ __forceinline__ unsigned long long packscreen(float v, int n) {
  unsigned u = __float_as_uint(v);
  u = (u >> 31) ? ~u : (u | 0x80000000u);
  return ((unsigned long long)u << 32) | (unsigned)n;
}

// ---------- prep: Wf=Wk@W1k (fp64 math, fp32 store), Q, qbT; c12; zero cells ----------
__global__ __launch_bounds__(128) void kprep(
    const float* __restrict__ pe, const float* __restrict__ Wq,
    const float* __restrict__ bq, const float* __restrict__ Wk,
    const float* __restrict__ bk, const float* __restrict__ W1,
    const float* __restrict__ b1, const float* __restrict__ w2,
    float* __restrict__ Wf32, double* __restrict__ qbT,
    float* __restrict__ Qm, unsigned long long* __restrict__ cells,
    double2* __restrict__ c12) {
  __shared__ float L[512];
  __shared__ double Ld[128];
  const int t = threadIdx.x;
  const int bid = blockIdx.x;
  if (bid < 256) {
    L[t] = Wk[bid * 128 + t];
    __syncthreads();
    double acc = 0.0;
    #pragma unroll 16
    for (int j = 0; j < 128; ++j)
      acc = fma((double)L[j], (double)W1[(128 + j) * 128 + t], acc);
    Wf32[bid * 128 + t] = (float)acc;
  } else if (bid < 320) {
    const int b = bid - 256;
    #pragma unroll
    for (int i = 0; i < 4; ++i) L[t + 128 * i] = pe[b * 512 + t + 128 * i];
    __syncthreads();
    double q = (double)bq[t];
    #pragma unroll 16
    for (int f = 0; f < 512; ++f)
      q = fma((double)L[f], (double)Wq[f * 128 + t], q);
    Qm[b * 128 + t] = (float)q;   // epilogue path stays fp32
    Ld[t] = q;
    __syncthreads();
    // qb[b,d=t] = Q@W1[:128] + b1 + bk@W1[128:]; store transposed qbT[d][b]
    double acc = (double)b1[t];
    #pragma unroll 8
    for (int j = 0; j < 128; ++j) {
      acc = fma(Ld[j], (double)W1[j * 128 + t], acc);
      acc = fma((double)bk[j], (double)W1[(128 + j) * 128 + t], acc);
    }
    qbT[t * 64 + b] = acc;
  } else {
    for (int i = t; i < 1280; i += 128) cells[i] = 0ull;
    const double w2d = (double)w2[t];
    c12[t] = make_double2(0.55 * w2d, 0.45 * w2d);
  }
}

// ---------- ksim: kp(fp32 GEMM) + sim(fp64) -> simg[64][20000] (NO atomics) ----------
// v2 geometry (1250 blocks x 256 thr, 16 genes/block, LDS 40 KB -> 4 blocks/CU)
// + counted-wait W pipeline: register-double-buffered W tile with RAW
// s_barrier + lgkmcnt(0)-only drains. __syncthreads emits vmcnt(0) before
// s_barrier [HIP-compiler], exposing ~300cy of L2 latency per tile between
// barriers; the raw-barrier form lets the next tile's 4 global_load_dwordx4
// stay in flight across the barrier and complete under compute (the compiler
// auto-inserts the data-dep vmcnt wait before the consuming ds_write).
// Race audit: Wt write->read = per-thread lgkmcnt(0) + barrier (writes
// visible); read->next-write = reaching the barrier implies fmas consumed the
// ds_read data (compiler waits before use); geL staging drained by tile-0
// lgkmcnt(0); named wrA/wrB (no dynamic reg indexing); uniform control flow.
// Bit-exactness: identical fma sequence (f ascending, same w/gv order), same
// values -> kp and simg bit-identical to R5/R8.
__global__ __launch_bounds__(256) void ksim(
    const float* __restrict__ ge, const float* __restrict__ Wf32,
    const double* __restrict__ qbT, const double2* __restrict__ c12,
    float* __restrict__ simg) {
  __shared__ double SBd[2048];   // 16 KB: phase1 geL; phase2 simLf [64][17]
  __shared__ float Wt[4096];     // 16 KB: one 32-f x 128-d W tile
  __shared__ float kpL[2048];    // 8 KB: kp[16][128]
  float* geL = (float*)SBd;
  float* simLf = (float*)SBd;
  const int t = threadIdx.x;
  const int wv = t >> 6;
  const int lane = t & 63;
  const int g0 = blockIdx.x * 16;     // 1250 blocks * 16 genes

  // stage ge tile (16 genes x 256 f) -> LDS: 4 independent float4 per thread
  // (ds_writes drained by the tile-0 lgkmcnt(0) + barrier below)
  {
    const float4* src = (const float4*)(ge + (size_t)g0 * 256);
    float4* dst = (float4*)geL;
    #pragma unroll
    for (int i = 0; i < 4; ++i) dst[t + i * 256] = src[t + i * 256];
  }

  // ---- phase 1: fp32 GEMM, W reg-double-buffered into one LDS tile ----
  float acc[4][2];
  #pragma unroll
  for (int j = 0; j < 4; ++j) { acc[j][0] = 0.f; acc[j][1] = 0.f; }
  const float* gL = geL + wv * 4 * 256;
  const float4* wsrc = (const float4*)Wf32;   // tile stride = 1024 float4

  auto compute = [&](int tile) {
    #pragma unroll
    for (int fr = 0; fr < 32; fr += 4) {
      const int f0 = tile * 32 + fr;
      const float2 w0 = *(const float2*)(Wt + (fr + 0) * 128 + 2 * lane);
      const float2 w1 = *(const float2*)(Wt + (fr + 1) * 128 + 2 * lane);
      const float2 w2 = *(const float2*)(Wt + (fr + 2) * 128 + 2 * lane);
      const float2 w3 = *(const float2*)(Wt + (fr + 3) * 128 + 2 * lane);
      #pragma unroll
      for (int j = 0; j < 4; ++j) {
        const float4 gv = *(const float4*)(gL + j * 256 + f0);  // LDS broadcast
        acc[j][0] = fmaf(gv.x, w0.x, acc[j][0]);
        acc[j][1] = fmaf(gv.x, w0.y, acc[j][1]);
        acc[j][0] = fmaf(gv.y, w1.x, acc[j][0]);
        acc[j][1] = fmaf(gv.y, w1.y, acc[j][1]);
        acc[j][0] = fmaf(gv.z, w2.x, acc[j][0]);
        acc[j][1] = fmaf(gv.z, w2.y, acc[j][1]);
        acc[j][0] = fmaf(gv.w, w3.x, acc[j][0]);
        acc[j][1] = fmaf(gv.w, w3.y, acc[j][1]);
      }
    }
  };

  float4 wrA[4], wrB[4];
  #pragma unroll
  for (int i = 0; i < 4; ++i) wrA[i] = wsrc[t + i * 256];     // tile 0 -> regs

  for (int tp = 0; tp < 4; ++tp) {   // tile pair (2tp, 2tp+1); NOT unrolled
    // ---- even tile 2tp: publish wrA -> Wt, prefetch tile 2tp+1 -> wrB ----
    asm volatile("s_waitcnt lgkmcnt(0)" ::: "memory");  // my LDS ops done
    __builtin_amdgcn_s_barrier();                       // Wt free (all waves)
    {
      float4* wdst = (float4*)Wt;
      #pragma unroll
      for (int i = 0; i < 4; ++i) wdst[t + i * 256] = wrA[i];
    }
    {
      const float4* s2 = wsrc + (2 * tp + 1) * 1024;
      #pragma unroll
      for (int i = 0; i < 4; ++i) wrB[i] = s2[t + i * 256];   // in flight
    }
    asm volatile("s_waitcnt lgkmcnt(0)" ::: "memory");  // Wt writes done
    __builtin_amdgcn_s_barrier();                       // Wt visible
    compute(2 * tp);
    // ---- odd tile 2tp+1: publish wrB -> Wt, prefetch tile 2tp+2 -> wrA ----
    asm volatile("s_waitcnt lgkmcnt(0)" ::: "memory");
    __builtin_amdgcn_s_barrier();
    {
      float4* wdst = (float4*)Wt;
      #pragma unroll
      for (int i = 0; i < 4; ++i) wdst[t + i * 256] = wrB[i];
    }
    if (tp < 3) {
      const float4* s2 = wsrc + (2 * tp + 2) * 1024;
      #pragma unroll
      for (int i = 0; i < 4; ++i) wrA[i] = s2[t + i * 256];
    }
    asm volatile("s_waitcnt lgkmcnt(0)" ::: "memory");
    __builtin_amdgcn_s_barrier();
    compute(2 * tp + 1);
  }

  __syncthreads();   // full drain once: geL reads done (SBd reused as simLf)
  #pragma unroll
  for (int j = 0; j < 4; ++j)
    ((float2*)(kpL + (wv * 4 + j) * 128))[lane] =
        make_float2(acc[j][0], acc[j][1]);
  __syncthreads();

  // ---- phase 2: fp64 sim (4 genes/wave, lane = batch) ----
  double s[4];
  #pragma unroll
  for (int j = 0; j < 4; ++j) s[j] = 0.0;
  for (int dd = 0; dd < 128; ++dd) {
    const double2 cc = c12[dd];                   // uniform -> s_load
    const double qv = qbT[dd * 64 + lane];        // coalesced, L1-hot
    #pragma unroll
    for (int j = 0; j < 4; ++j) {
      const double kv = (double)kpL[(wv + j * 4) * 128 + dd];  // broadcast
      const double tt = qv + kv;
      s[j] = fma(tt, cc.x, s[j]);
      s[j] = fma(fabs(tt), cc.y, s[j]);
    }
  }
  #pragma unroll
  for (int j = 0; j < 4; ++j)
    simLf[lane * 17 + (wv + j * 4)] = (float)(2.0 * s[j]);
  __syncthreads();

  // ---- transpose-store: thread t -> b = t>>2, gene-chunk = t&3 (float4) ----
  {
    const int b = t >> 2;
    const int gc = t & 3;
    float4 v;
    v.x = simLf[b * 17 + gc * 4 + 0];
    v.y = simLf[b * 17 + gc * 4 + 1];
    v.z = simLf[b * 17 + gc * 4 + 2];
    v.w = simLf[b * 17 + gc * 4 + 3];
    *(float4*)(simg + (size_t)b * NG + g0 + gc * 4) = v;
  }
}

// ---------- kargmax: 2 windows per cell, float4-chunk screen, atomicMax merge ----------
// Instruction-floor'd (R3/R4/R8: 81-86 us across 3 loop structures, VALUBusy
// 87-93%; ~70 irreducible threefry inst/eval x 25.6M evals). Unchanged.
__global__ __launch_bounds__(256) void kargmax(
    const float* __restrict__ simg, unsigned long long* __restrict__ cells) {
  __shared__ unsigned long long R1s[4], R2s[4];
  const int cell = blockIdx.x >> 1;            // = b*20 + k
  const int wdw = blockIdx.x & 1;
  const int t = threadIdx.x;
  const int wv = t >> 6;
  const int lane = t & 63;
  const int b = (unsigned)cell / 20u;
  const float* sb = simg + (size_t)b * NG;
  const unsigned ib = (unsigned)cell * (unsigned)NG;
  const int base = wdw * 10000;

  float m1 = -3e38f, m2 = -3e38f;
  int n1 = -1, n2 = -1;
  for (int c = t; c < 2500; c += 256) {
    const int n0 = base + c * 4;
    const float4 sv = *(const float4*)(sb + n0);     // coalesced 16B
    const unsigned bb0 = tfbits(ib + (unsigned)n0);
    const unsigned bb1 = tfbits(ib + (unsigned)(n0 + 1));
    const unsigned bb2 = tfbits(ib + (unsigned)(n0 + 2));
    const unsigned bb3 = tfbits(ib + (unsigned)(n0 + 3));
    const float s0 = sv.x + gumbel32(bb0);
    const float s1 = sv.y + gumbel32(bb1);
    const float s2 = sv.z + gumbel32(bb2);
    const float s3 = sv.w + gumbel32(bb3);
    if (s0 > m1) { m2 = m1; n2 = n1; m1 = s0; n1 = n0; }
    else if (s0 > m2) { m2 = s0; n2 = n0; }
    if (s1 > m1) { m2 = m1; n2 = n1; m1 = s1; n1 = n0 + 1; }
    else if (s1 > m2) { m2 = s1; n2 = n0 + 1; }
    if (s2 > m1) { m2 = m1; n2 = n1; m1 = s2; n1 = n0 + 2; }
    else if (s2 > m2) { m2 = s2; n2 = n0 + 2; }
    if (s3 > m1) { m2 = m1; n2 = n1; m1 = s3; n1 = n0 + 3; }
    else if (s3 > m2) { m2 = s3; n2 = n0 + 3; }
  }
  unsigned long long p1 = packscreen(m1, n1);
  unsigned long long p2 = packscreen(m2, n2);
  // wave top-2 butterfly: merge sorted pairs (p1>=p2), (q1>=q2)
  #pragma unroll
  for (int off = 32; off; off >>= 1) {
    unsigned long long q1 = __shfl_xor(p1, off, 64);
    unsigned long long q2 = __shfl_xor(p2, off, 64);
    if (q1 > p1) {
      unsigned long long t1 = p1;
      p1 = q1;
      p2 = (q2 > t1) ? q2 : t1;
    } else {
      p2 = (q1 > p2) ? q1 : p2;
    }
  }
  if (lane == 0) { R1s[wv] = p1; R2s[wv] = p2; }
  __syncthreads();
  if (t == 0) {
    unsigned long long P1 = R1s[0], P2 = R2s[0];
    #pragma unroll
    for (int w = 1; w < 4; ++w) {
      unsigned long long q1 = R1s[w], q2 = R2s[w];
      if (q1 > P1) {
        unsigned long long t1 = P1;
        P1 = q1;
        P2 = (q2 > t1) ? q2 : t1;
      } else {
        P2 = (q1 > P2) ? q1 : P2;
      }
    }
    const int w1 = (int)(P1 & 0xFFFFFFFFull);
    const int w2i = (int)(P2 & 0xFFFFFFFFull);
    const unsigned bb1 = tfbits(ib + (unsigned)w1);
    const float s1f = sb[w1];
    const float sc1 = s1f + gumbel32(bb1);
    unsigned long long pb = packcell((double)s1f + gumbel64(bb1), w1);
    if (w2i >= 0) {
      const unsigned bb2 = tfbits(ib + (unsigned)w2i);
      const float s2f = sb[w2i];
      const float sc2 = s2f + gumbel32(bb2);
      if ((sc1 - sc2) < 1e-4f) {
        const unsigned long long u2 =
            packcell((double)s2f + gumbel64(bb2), w2i);
        if (u2 > pb) pb = u2;
      }
    }
    atomicMax(&cells[cell], pb);
  }
}

// ---------- epilogue (fp32): 5 interleaved V-GEMVs per wave, softmax over K, context ----------
__global__ __launch_bounds__(256) void kfinal(
    const float* __restrict__ ge, const float* __restrict__ Wv,
    const float* __restrict__ bv, const float* __restrict__ Qm,
    const unsigned long long* __restrict__ cells, float* __restrict__ out) {
  const int b = blockIdx.x;
  const int t = threadIdx.x;
  const int wv = t >> 6;
  const int lane = t & 63;
  __shared__ float sc[20];
  __shared__ float ctxp[4][128];
  const float2 qv = ((const float2*)(Qm + b * 128))[lane];
  const float2 bvv = ((const float2*)bv)[lane];
  const float* gr[5];
  float2 V[5];
  #pragma unroll
  for (int j = 0; j < 5; ++j) {
    const unsigned long long cell = cells[b * 20 + wv * 5 + j];
    const int n = 32767 - (int)(cell & 0x7FFFull);
    gr[j] = ge + (size_t)n * 256;
    V[j] = bvv;
  }
  for (int f = 0; f < 256; f += 4) {
    const float2 w0 = ((const float2*)(Wv + (size_t)(f + 0) * 128))[lane];
    const float2 w1 = ((const float2*)(Wv + (size_t)(f + 1) * 128))[lane];
    const float2 w2_ = ((const float2*)(Wv + (size_t)(f + 2) * 128))[lane];
    const float2 w3 = ((const float2*)(Wv + (size_t)(f + 3) * 128))[lane];
    #pragma unroll
    for (int j = 0; j < 5; ++j) {
      const float4 gv = *(const float4*)(gr[j] + f);   // uniform -> s_load
      V[j].x = fmaf(gv.x, w0.x, V[j].x); V[j].y = fmaf(gv.x, w0.y, V[j].y);
      V[j].x = fmaf(gv.y, w1.x, V[j].x); V[j].y = fmaf(gv.y, w1.y, V[j].y);
      V[j].x = fmaf(gv.z, w2_.x, V[j].x); V[j].y = fmaf(gv.z, w2_.y, V[j].y);
      V[j].x = fmaf(gv.w, w3.x, V[j].x); V[j].y = fmaf(gv.w, w3.y, V[j].y);
    }
  }
  #pragma unroll
  for (int j = 0; j < 5; ++j) {
    float pr = qv.x * V[j].x + qv.y * V[j].y;
    #pragma unroll
    for (int off = 32; off; off >>= 1) pr += __shfl_xor(pr, off, 64);
    if (lane == 0) sc[wv * 5 + j] = pr * 0.08838834764831845f;  // 1/sqrt(128)
  }
  __syncthreads();
  float m = -3.0e38f;
  #pragma unroll
  for (int i = 0; i < 20; ++i) m = fmaxf(m, sc[i]);
  float s = 0.f;
  #pragma unroll
  for (int i = 0; i < 20; ++i) s += expf(sc[i] - m);
  const float inv = 1.0f / s;
  float c0 = 0.f, c1 = 0.f;
  #pragma unroll
  for (int j = 0; j < 5; ++j) {
    const float wk = expf(sc[wv * 5 + j] - m) * inv;
    c0 = fmaf(wk, V[j].x, c0);
    c1 = fmaf(wk, V[j].y, c1);
  }
  ctxp[wv][2 * lane] = c0;
  ctxp[wv][2 * lane + 1] = c1;
  __syncthreads();
  if (t < 128)
    out[b * 128 + t] = (ctxp[0][t] + ctxp[1][t]) + (ctxp[2][t] + ctxp[3][t]);
}

extern "C" void kernel_launch(void* const* d_in, const int* in_sizes, int n_in,
                              void* d_out, int out_size, void* d_ws, size_t ws_size,
                              hipStream_t stream) {
  (void)in_sizes; (void)n_in; (void)out_size; (void)ws_size;
  const float* pe = (const float*)d_in[0];
  const float* ge = (const float*)d_in[1];
  const float* Wq = (const float*)d_in[2];
  const float* bq = (const float*)d_in[3];
  const float* Wk = (const float*)d_in[4];
  const float* bk = (const float*)d_in[5];
  const float* Wv = (const float*)d_in[6];
  const float* bvp = (const float*)d_in[7];
  const float* W1 = (const float*)d_in[8];
  const float* b1 = (const float*)d_in[9];
  const float* w2 = (const float*)d_in[10];
  // d_in[11] = b2: uniform over n -> cancels in argmax; absent from output path.

  char* w = (char*)d_ws;
  float* Wf32 = (float*)w;                               // 131072 B
  double* qbT = (double*)(w + 131072);                   // 65536 B
  float* Qm = (float*)(w + 196608);                      // 32768 B
  unsigned long long* cells =
      (unsigned long long*)(w + 229376);                 // 10240 B
  double2* c12 = (double2*)(w + 239616);                 // 2048 B
  float* simg = (float*)(w + 262144);                    // 5,120,000 B (~5.4 MB total)
  float* out = (float*)d_out;

  kprep<<<dim3(321), dim3(128), 0, stream>>>(pe, Wq, bq, Wk, bk, W1, b1, w2,
                                             Wf32, qbT, Qm, cells, c12);
  ksim<<<dim3(1250), dim3(256), 0, stream>>>(ge, Wf32, qbT, c12, simg);
  kargmax<<<dim3(2560), dim3(256), 0, stream>>>(simg, cells);
  kfinal<<<dim3(64), dim3(256), 0, stream>>>(ge, Wv, bvp, Qm, cells, out);
}

// Round 11
// 262.603 us; speedup vs baseline: 1.0757x; 1.0757x over previous
//
#include <hip/hip_runtime.h>

#define NG 20000

// single-instruction rotate (v_alignbit_b32): rotl(x,r) == alignbit(x,x,32-r)
__device__ __forceinline__ unsigned rotl32(unsigned x, int r) {
  return __builtin_amdgcn_alignbit(x, x, 32 - r);
}

// ---------- JAX threefry2x32, key = (0, 42) ----------
__device__ __forceinline__ void threefry2x32(unsigned x0, unsigned x1,
                                             unsigned& o0, unsigned& o1) {
  const unsigned ks0 = 0u;
  const unsigned ks1 = 42u;
  const unsigned ks2 = 0x1BD11BDAu ^ 0u ^ 42u;
  x0 += ks0; x1 += ks1;
#define TFR(r) { x0 += x1; x1 = rotl32(x1, (r)); x1 ^= x0; }
  TFR(13) TFR(15) TFR(26) TFR(6)
  x0 += ks1; x1 += ks2 + 1u;
  TFR(17) TFR(29) TFR(16) TFR(24)
  x0 += ks2; x1 += ks0 + 2u;
  TFR(13) TFR(15) TFR(26) TFR(6)
  x0 += ks0; x1 += ks1 + 3u;
  TFR(17) TFR(29) TFR(16) TFR(24)
  x0 += ks1; x1 += ks2 + 4u;
  TFR(13) TFR(15) TFR(26) TFR(6)
  x0 += ks2; x1 += ks0 + 5u;
#undef TFR
  o0 = x0; o1 = x1;
}

// JAX threefry_partitionable: bits(i) = o0 ^ o1 of threefry((0,42),(0,i))
__device__ __forceinline__ unsigned tfbits(unsigned ctr) {
  unsigned o0, o1;
  threefry2x32(0u, ctr, o0, o1);
  return o0 ^ o1;
}

// fp32 fast-screen gumbel, constant-folded: g = -ln2*log2(-log2(u)) - ln(ln2)
__device__ __forceinline__ float gumbel32(unsigned bits) {
  float f = __uint_as_float((bits >> 9) | 0x3f800000u) - 1.0f;
  float u = fmaxf(f, 1.17549435e-38f);
  const float l2u = __log2f(u);                     // strictly < 0
  return fmaf(-0.69314718056f, __log2f(-l2u), 0.3665129206f);
}

// exact fp64 gumbel; u is a 23-bit dyadic rational, exact in double
__device__ __forceinline__ double gumbel64(unsigned bits) {
  float f = __uint_as_float((bits >> 9) | 0x3f800000u) - 1.0f;
  double u = (double)fmaxf(f, 1.17549435e-38f);
  return -log(-log(u));
}

// pack fp64 score (top 49 monotone bits) + 15-bit (32767-n): u64 max == (score, then smaller n)
__device__ __forceinline__ unsigned long long packcell(double v, int n) {
  unsigned long long u = (unsigned long long)__double_as_longlong(v);
  u = (u >> 63) ? ~u : (u | 0x8000000000000000ull);
  return (u & 0xFFFFFFFFFFFF8000ull) | (unsigned long long)(32767 - n);
}

// monotone fp32 pack (high 32) + gene index (low 32) for top-2 reduction
__device__ __forceinline__ unsigned long long packscreen(float v, int n) {
  unsigned u = __float_as_uint(v);
  u = (u >> 31) ? ~u : (u | 0x80000000u);
  return ((unsigned long long)u << 32) | (unsigned)n;
}

// ---------- prep: Wf=Wk@W1k (fp64 math, fp32 store), Q, qbT; c12; zero cells ----------
__global__ __launch_bounds__(128) void kprep(
    const float* __restrict__ pe, const float* __restrict__ Wq,
    const float* __restrict__ bq, const float* __restrict__ Wk,
    const float* __restrict__ bk, const float* __restrict__ W1,
    const float* __restrict__ b1, const float* __restrict__ w2,
    float* __restrict__ Wf32, double* __restrict__ qbT,
    float* __restrict__ Qm, unsigned long long* __restrict__ cells,
    double2* __restrict__ c12) {
  __shared__ float L[512];
  __shared__ double Ld[128];
  const int t = threadIdx.x;
  const int bid = blockIdx.x;
  if (bid < 256) {
    L[t] = Wk[bid * 128 + t];
    __syncthreads();
    double acc = 0.0;
    #pragma unroll 16
    for (int j = 0; j < 128; ++j)
      acc = fma((double)L[j], (double)W1[(128 + j) * 128 + t], acc);
    Wf32[bid * 128 + t] = (float)acc;
  } else if (bid < 320) {
    const int b = bid - 256;
    #pragma unroll
    for (int i = 0; i < 4; ++i) L[t + 128 * i] = pe[b * 512 + t + 128 * i];
    __syncthreads();
    double q = (double)bq[t];
    #pragma unroll 16
    for (int f = 0; f < 512; ++f)
      q = fma((double)L[f], (double)Wq[f * 128 + t], q);
    Qm[b * 128 + t] = (float)q;   // epilogue path stays fp32
    Ld[t] = q;
    __syncthreads();
    // qb[b,d=t] = Q@W1[:128] + b1 + bk@W1[128:]; store transposed qbT[d][b]
    double acc = (double)b1[t];
    #pragma unroll 8
    for (int j = 0; j < 128; ++j) {
      acc = fma(Ld[j], (double)W1[j * 128 + t], acc);
      acc = fma((double)bk[j], (double)W1[(128 + j) * 128 + t], acc);
    }
    qbT[t * 64 + b] = acc;
  } else {
    for (int i = t; i < 1280; i += 128) cells[i] = 0ull;
    const double w2d = (double)w2[t];
    c12[t] = make_double2(0.55 * w2d, 0.45 * w2d);
  }
}

// ---------- ksim: kp(fp32 GEMM) + sim(fp64) -> simg[64][20000] (NO atomics) ----------
// v2: measured-best ksim (R5/R8). 1250 blocks x 256 thr, 16 genes/block,
// LDS 40 KB -> 4 blocks/CU. W staged in cooperative 32-f LDS tiles with plain
// __syncthreads (R10 showed hand-rolled raw-barrier/lgkmcnt pipelining
// REGRESSES ~22 us: asm "memory" clobbers defeat compiler scheduling —
// learn_hip m141-class failure). Wave wv owns genes wv*4..wv*4+3; thread owns
// d = {2*lane, 2*lane+1}; per-acc fma order f-ascending -> kp bit-identical.
// Wt reads: bank = 2*lane mod 32 -> 2-way conflict = free. Gene reads:
// wave-uniform addr -> LDS broadcast.
// Phase 2: fp64 sim, wave wv computes genes {wv,wv+4,wv+8,wv+12}, lane =
// batch; identical fp64 op order. Then transpose simLf via LDS, coalesced
// float4 store.
__global__ __launch_bounds__(256) void ksim(
    const float* __restrict__ ge, const float* __restrict__ Wf32,
    const double* __restrict__ qbT, const double2* __restrict__ c12,
    float* __restrict__ simg) {
  __shared__ double SBd[2048];   // 16 KB: phase1 geL; phase2 simLf [64][17]
  __shared__ float Wt[4096];     // 16 KB: one 32-f x 128-d W tile
  __shared__ float kpL[2048];    // 8 KB: kp[16][128]
  float* geL = (float*)SBd;
  float* simLf = (float*)SBd;
  const int t = threadIdx.x;
  const int wv = t >> 6;
  const int lane = t & 63;
  const int g0 = blockIdx.x * 16;     // 1250 blocks * 16 genes

  // stage ge tile (16 genes x 256 f) -> LDS: 4 independent float4 per thread
  // (ordered before first compute by the first in-loop barrier)
  {
    const float4* src = (const float4*)(ge + (size_t)g0 * 256);
    float4* dst = (float4*)geL;
    #pragma unroll
    for (int i = 0; i < 4; ++i) dst[t + i * 256] = src[t + i * 256];
  }

  // ---- phase 1: fp32 GEMM, W in single-buffered 32-f LDS tiles ----
  float acc[4][2];
  #pragma unroll
  for (int j = 0; j < 4; ++j) { acc[j][0] = 0.f; acc[j][1] = 0.f; }
  const float* gL = geL + wv * 4 * 256;

  for (int tile = 0; tile < 8; ++tile) {
    __syncthreads();   // tile 0: geL staged; else: prev tile's Wt reads done
    {
      const float4* wsrc = (const float4*)(Wf32 + tile * 32 * 128);
      float4* wdst = (float4*)Wt;
      #pragma unroll
      for (int i = 0; i < 4; ++i) wdst[t + i * 256] = wsrc[t + i * 256];
    }
    __syncthreads();
    #pragma unroll
    for (int fr = 0; fr < 32; fr += 4) {
      const int f0 = tile * 32 + fr;
      const float2 w0 = *(const float2*)(Wt + (fr + 0) * 128 + 2 * lane);
      const float2 w1 = *(const float2*)(Wt + (fr + 1) * 128 + 2 * lane);
      const float2 w2 = *(const float2*)(Wt + (fr + 2) * 128 + 2 * lane);
      const float2 w3 = *(const float2*)(Wt + (fr + 3) * 128 + 2 * lane);
      #pragma unroll
      for (int j = 0; j < 4; ++j) {
        const float4 gv = *(const float4*)(gL + j * 256 + f0);  // LDS broadcast
        acc[j][0] = fmaf(gv.x, w0.x, acc[j][0]);
        acc[j][1] = fmaf(gv.x, w0.y, acc[j][1]);
        acc[j][0] = fmaf(gv.y, w1.x, acc[j][0]);
        acc[j][1] = fmaf(gv.y, w1.y, acc[j][1]);
        acc[j][0] = fmaf(gv.z, w2.x, acc[j][0]);
        acc[j][1] = fmaf(gv.z, w2.y, acc[j][1]);
        acc[j][0] = fmaf(gv.w, w3.x, acc[j][0]);
        acc[j][1] = fmaf(gv.w, w3.y, acc[j][1]);
      }
    }
  }

  __syncthreads();   // geL reads done (SBd about to be reused as simLf)
  #pragma unroll
  for (int j = 0; j < 4; ++j)
    ((float2*)(kpL + (wv * 4 + j) * 128))[lane] =
        make_float2(acc[j][0], acc[j][1]);
  __syncthreads();

  // ---- phase 2: fp64 sim (4 genes/wave, lane = batch) ----
  double s[4];
  #pragma unroll
  for (int j = 0; j < 4; ++j) s[j] = 0.0;
  for (int dd = 0; dd < 128; ++dd) {
    const double2 cc = c12[dd];                   // uniform -> s_load
    const double qv = qbT[dd * 64 + lane];        // coalesced, L1-hot
    #pragma unroll
    for (int j = 0; j < 4; ++j) {
      const double kv = (double)kpL[(wv + j * 4) * 128 + dd];  // broadcast
      const double tt = qv + kv;
      s[j] = fma(tt, cc.x, s[j]);
      s[j] = fma(fabs(tt), cc.y, s[j]);
    }
  }
  #pragma unroll
  for (int j = 0; j < 4; ++j)
    simLf[lane * 17 + (wv + j * 4)] = (float)(2.0 * s[j]);
  __syncthreads();

  // ---- transpose-store: thread t -> b = t>>2, gene-chunk = t&3 (float4) ----
  {
    const int b = t >> 2;
    const int gc = t & 3;
    float4 v;
    v.x = simLf[b * 17 + gc * 4 + 0];
    v.y = simLf[b * 17 + gc * 4 + 1];
    v.z = simLf[b * 17 + gc * 4 + 2];
    v.w = simLf[b * 17 + gc * 4 + 3];
    *(float4*)(simg + (size_t)b * NG + g0 + gc * 4) = v;
  }
}

// ---------- kargmax: 2 windows per cell, float4-chunk screen, atomicMax merge ----------
// Instruction-floor'd (R3/R4/R8: 81-86 us across 3 loop structures, VALUBusy
// 87-93%; ~70 irreducible threefry inst/eval x 25.6M evals; gumbel range 20.4
// >> sim spread -> no sound prune exists). Unchanged from R8.
__global__ __launch_bounds__(256) void kargmax(
    const float* __restrict__ simg, unsigned long long* __restrict__ cells) {
  __shared__ unsigned long long R1s[4], R2s[4];
  const int cell = blockIdx.x >> 1;            // = b*20 + k
  const int wdw = blockIdx.x & 1;
  const int t = threadIdx.x;
  const int wv = t >> 6;
  const int lane = t & 63;
  const int b = (unsigned)cell / 20u;
  const float* sb = simg + (size_t)b * NG;
  const unsigned ib = (unsigned)cell * (unsigned)NG;
  const int base = wdw * 10000;

  float m1 = -3e38f, m2 = -3e38f;
  int n1 = -1, n2 = -1;
  for (int c = t; c < 2500; c += 256) {
    const int n0 = base + c * 4;
    const float4 sv = *(const float4*)(sb + n0);     // coalesced 16B
    const unsigned bb0 = tfbits(ib + (unsigned)n0);
    const unsigned bb1 = tfbits(ib + (unsigned)(n0 + 1));
    const unsigned bb2 = tfbits(ib + (unsigned)(n0 + 2));
    const unsigned bb3 = tfbits(ib + (unsigned)(n0 + 3));
    const float s0 = sv.x + gumbel32(bb0);
    const float s1 = sv.y + gumbel32(bb1);
    const float s2 = sv.z + gumbel32(bb2);
    const float s3 = sv.w + gumbel32(bb3);
    if (s0 > m1) { m2 = m1; n2 = n1; m1 = s0; n1 = n0; }
    else if (s0 > m2) { m2 = s0; n2 = n0; }
    if (s1 > m1) { m2 = m1; n2 = n1; m1 = s1; n1 = n0 + 1; }
    else if (s1 > m2) { m2 = s1; n2 = n0 + 1; }
    if (s2 > m1) { m2 = m1; n2 = n1; m1 = s2; n1 = n0 + 2; }
    else if (s2 > m2) { m2 = s2; n2 = n0 + 2; }
    if (s3 > m1) { m2 = m1; n2 = n1; m1 = s3; n1 = n0 + 3; }
    else if (s3 > m2) { m2 = s3; n2 = n0 + 3; }
  }
  unsigned long long p1 = packscreen(m1, n1);
  unsigned long long p2 = packscreen(m2, n2);
  // wave top-2 butterfly: merge sorted pairs (p1>=p2), (q1>=q2)
  #pragma unroll
  for (int off = 32; off; off >>= 1) {
    unsigned long long q1 = __shfl_xor(p1, off, 64);
    unsigned long long q2 = __shfl_xor(p2, off, 64);
    if (q1 > p1) {
      unsigned long long t1 = p1;
      p1 = q1;
      p2 = (q2 > t1) ? q2 : t1;
    } else {
      p2 = (q1 > p2) ? q1 : p2;
    }
  }
  if (lane == 0) { R1s[wv] = p1; R2s[wv] = p2; }
  __syncthreads();
  if (t == 0) {
    unsigned long long P1 = R1s[0], P2 = R2s[0];
    #pragma unroll
    for (int w = 1; w < 4; ++w) {
      unsigned long long q1 = R1s[w], q2 = R2s[w];
      if (q1 > P1) {
        unsigned long long t1 = P1;
        P1 = q1;
        P2 = (q2 > t1) ? q2 : t1;
      } else {
        P2 = (q1 > P2) ? q1 : P2;
      }
    }
    const int w1 = (int)(P1 & 0xFFFFFFFFull);
    const int w2i = (int)(P2 & 0xFFFFFFFFull);
    const unsigned bb1 = tfbits(ib + (unsigned)w1);
    const float s1f = sb[w1];
    const float sc1 = s1f + gumbel32(bb1);
    unsigned long long pb = packcell((double)s1f + gumbel64(bb1), w1);
    if (w2i >= 0) {
      const unsigned bb2 = tfbits(ib + (unsigned)w2i);
      const float s2f = sb[w2i];
      const float sc2 = s2f + gumbel32(bb2);
      if ((sc1 - sc2) < 1e-4f) {
        const unsigned long long u2 =
            packcell((double)s2f + gumbel64(bb2), w2i);
        if (u2 > pb) pb = u2;
      }
    }
    atomicMax(&cells[cell], pb);
  }
}

// ---------- epilogue (fp32): 5 interleaved V-GEMVs per wave, softmax over K, context ----------
__global__ __launch_bounds__(256) void kfinal(
    const float* __restrict__ ge, const float* __restrict__ Wv,
    const float* __restrict__ bv, const float* __restrict__ Qm,
    const unsigned long long* __restrict__ cells, float* __restrict__ out) {
  const int b = blockIdx.x;
  const int t = threadIdx.x;
  const int wv = t >> 6;
  const int lane = t & 63;
  __shared__ float sc[20];
  __shared__ float ctxp[4][128];
  const float2 qv = ((const float2*)(Qm + b * 128))[lane];
  const float2 bvv = ((const float2*)bv)[lane];
  const float* gr[5];
  float2 V[5];
  #pragma unroll
  for (int j = 0; j < 5; ++j) {
    const unsigned long long cell = cells[b * 20 + wv * 5 + j];
    const int n = 32767 - (int)(cell & 0x7FFFull);
    gr[j] = ge + (size_t)n * 256;
    V[j] = bvv;
  }
  for (int f = 0; f < 256; f += 4) {
    const float2 w0 = ((const float2*)(Wv + (size_t)(f + 0) * 128))[lane];
    const float2 w1 = ((const float2*)(Wv + (size_t)(f + 1) * 128))[lane];
    const float2 w2_ = ((const float2*)(Wv + (size_t)(f + 2) * 128))[lane];
    const float2 w3 = ((const float2*)(Wv + (size_t)(f + 3) * 128))[lane];
    #pragma unroll
    for (int j = 0; j < 5; ++j) {
      const float4 gv = *(const float4*)(gr[j] + f);   // uniform -> s_load
      V[j].x = fmaf(gv.x, w0.x, V[j].x); V[j].y = fmaf(gv.x, w0.y, V[j].y);
      V[j].x = fmaf(gv.y, w1.x, V[j].x); V[j].y = fmaf(gv.y, w1.y, V[j].y);
      V[j].x = fmaf(gv.z, w2_.x, V[j].x); V[j].y = fmaf(gv.z, w2_.y, V[j].y);
      V[j].x = fmaf(gv.w, w3.x, V[j].x); V[j].y = fmaf(gv.w, w3.y, V[j].y);
    }
  }
  #pragma unroll
  for (int j = 0; j < 5; ++j) {
    float pr = qv.x * V[j].x + qv.y * V[j].y;
    #pragma unroll
    for (int off = 32; off; off >>= 1) pr += __shfl_xor(pr, off, 64);
    if (lane == 0) sc[wv * 5 + j] = pr * 0.08838834764831845f;  // 1/sqrt(128)
  }
  __syncthreads();
  float m = -3.0e38f;
  #pragma unroll
  for (int i = 0; i < 20; ++i) m = fmaxf(m, sc[i]);
  float s = 0.f;
  #pragma unroll
  for (int i = 0; i < 20; ++i) s += expf(sc[i] - m);
  const float inv = 1.0f / s;
  float c0 = 0.f, c1 = 0.f;
  #pragma unroll
  for (int j = 0; j < 5; ++j) {
    const float wk = expf(sc[wv * 5 + j] - m) * inv;
    c0 = fmaf(wk, V[j].x, c0);
    c1 = fmaf(wk, V[j].y, c1);
  }
  ctxp[wv][2 * lane] = c0;
  ctxp[wv][2 * lane + 1] = c1;
  __syncthreads();
  if (t < 128)
    out[b * 128 + t] = (ctxp[0][t] + ctxp[1][t]) + (ctxp[2][t] + ctxp[3][t]);
}

extern "C" void kernel_launch(void* const* d_in, const int* in_sizes, int n_in,
                              void* d_out, int out_size, void* d_ws, size_t ws_size,
                              hipStream_t stream) {
  (void)in_sizes; (void)n_in; (void)out_size; (void)ws_size;
  const float* pe = (const float*)d_in[0];
  const float* ge = (const float*)d_in[1];
  const float* Wq = (const float*)d_in[2];
  const float* bq = (const float*)d_in[3];
  const float* Wk = (const float*)d_in[4];
  const float* bk = (const float*)d_in[5];
  const float* Wv = (const float*)d_in[6];
  const float* bvp = (const float*)d_in[7];
  const float* W1 = (const float*)d_in[8];
  const float* b1 = (const float*)d_in[9];
  const float* w2 = (const float*)d_in[10];
  // d_in[11] = b2: uniform over n -> cancels in argmax; absent from output path.

  char* w = (char*)d_ws;
  float* Wf32 = (float*)w;                               // 131072 B
  double* qbT = (double*)(w + 131072);                   // 65536 B
  float* Qm = (float*)(w + 196608);                      // 32768 B
  unsigned long long* cells =
      (unsigned long long*)(w + 229376);                 // 10240 B
  double2* c12 = (double2*)(w + 239616);                 // 2048 B
  float* simg = (float*)(w + 262144);                    // 5,120,000 B (~5.4 MB total)
  float* out = (float*)d_out;

  kprep<<<dim3(321), dim3(128), 0, stream>>>(pe, Wq, bq, Wk, bk, W1, b1, w2,
                                             Wf32, qbT, Qm, cells, c12);
  ksim<<<dim3(1250), dim3(256), 0, stream>>>(ge, Wf32, qbT, c12, simg);
  kargmax<<<dim3(2560), dim3(256), 0, stream>>>(simg, cells);
  kfinal<<<dim3(64), dim3(256), 0, stream>>>(ge, Wv, bvp, Qm, cells, out);
}